// Round 7
// baseline (168.135 us; speedup 1.0000x reference)
//
#include <hip/hip_runtime.h>
#include <hip/hip_fp16.h>
#include <math.h>

#define BB 8
#define CC 64
#define HH 128
#define WW 128
#define HO 64
#define WO 128
#define OC 64
#define HW (HH * WW)

typedef __attribute__((ext_vector_type(4))) float floatx4;
typedef __attribute__((ext_vector_type(8))) _Float16 half8;

__device__ __forceinline__ unsigned short f2h(float f) {
    __half h = __float2half(f);
    return __builtin_bit_cast(unsigned short, h);
}
__device__ __forceinline__ unsigned int packpair(float a, float b) {
    __half2 h = __floats2half2_rn(a, b);   // lo=a hi=b
    return __builtin_bit_cast(unsigned int, h);
}
// Per-wave fence: drain own LDS ops (in-order DS pipe); orders phases of ONE
// wave. No s_barrier anywhere in fused — waves are fully independent.
__device__ __forceinline__ void wave_fence() {
    asm volatile("s_waitcnt lgkmcnt(0)" ::: "memory");
}

// ---------------------------------------------------------------------------
// Kernel A (prep) — byte-identical to rounds 5-6.
// ---------------------------------------------------------------------------
__global__ __launch_bounds__(256) void prep(
    const float* __restrict__ x,
    const float* __restrict__ w_off, const float* __restrict__ w_msk,
    const float* __restrict__ w_conv,
    unsigned int* __restrict__ xP,
    unsigned short* __restrict__ Wom, unsigned short* __restrict__ W2)
{
    __shared__ float T[66][65];        // [w 0..64][c 0..63], stride 65
    int tid = threadIdx.x, bx = blockIdx.x;
    if (bx < 2048) {
        int wh = bx & 1, b = (bx >> 1) & 7, y = bx >> 4;
        int w0 = wh << 6;
        const float* xb = x + (((size_t)b * CC) * HH + y) * WW + w0;
#pragma unroll
        for (int i = 0; i < 4; ++i) {
            int idx = i * 256 + tid;             // 0..1023
            int cch = idx >> 4, f4 = (idx & 15) << 2;
            floatx4 v = *(const floatx4*)(xb + (size_t)cch * HW + f4);
            T[f4 + 0][cch] = v.x;
            T[f4 + 1][cch] = v.y;
            T[f4 + 2][cch] = v.z;
            T[f4 + 3][cch] = v.w;
        }
        if (tid < 64) {
            float e = 0.0f;
            if (w0 + 64 < WW) e = xb[(size_t)tid * HW + 64];
            T[64][tid] = e;
        }
        __syncthreads();
        int c4 = tid & 15;             // channel block (4c4..4c4+3)
        int wr = tid >> 4;             // 0..15
        size_t rowbase = (((size_t)b * HH + y) * WW) + w0;
#pragma unroll
        for (int j = 0; j < 4; ++j) {
            int w = 16 * j + wr;
            floatx4 a  = *(const floatx4*)&T[w][4 * c4];
            floatx4 bb = *(const floatx4*)&T[w + 1][4 * c4];
            uint4 d;
            d.x = packpair(a.x, bb.x);
            d.y = packpair(a.y, bb.y);
            d.z = packpair(a.z, bb.z);
            d.w = packpair(a.w, bb.w);
            *(uint4*)(xP + (rowbase + w) * 64 + 4 * c4) = d;
        }
    } else if (bx < 2120) {
        int i = (bx - 2048) * 256 + tid;     // < 18432 = 32*576
        int chn = i / 576, kk = i % 576;
        int xs = kk >> 6, cc = kk & 63;
        float v = 0.0f;
        if (chn < 18)      v = w_off[(chn * CC + cc) * 9 + xs];
        else if (chn < 27) v = w_msk[((chn - 18) * CC + cc) * 9 + xs];
        Wom[i] = f2h(v);
    } else {
        int i = (bx - 2120) * 256 + tid;     // < 36864
        int k = i % 9, cc = (i / 9) % CC, o = i / (CC * 9);
        W2[((size_t)k * OC + o) * CC + cc] = f2h(w_conv[i]);
    }
}

// ---------------------------------------------------------------------------
// Kernel B (fused), round-7 = round-6 structure with the LAUNCH BUG fixed:
// tiles = 8b * 64h * 8wt = 4096; 4 waves/block -> grid = 1024 (round 6
// launched 2048 -> g up to 8191 -> b up to 15 -> OOB xP reads + OOB out
// writes -> heap corruption/abort). Kernel body unchanged.
//
// Tile = 16 positions x all 64 output channels, owned by ONE wave.
// Block = 4 independent waves (disjoint 9.5KB LDS regions, no sharing,
// no __syncthreads). Latency hidden by TLP: 16 independent wave
// pipelines per CU (1024 blocks = 4 blocks/CU exactly resident).
//
// Per-wave phases (wave_fence = lgkmcnt(0) only, between phases):
//  1. stage slab Xs[3][18 cols][64ch] f16 from xP lows
//  2. om GEMM: M=32(27ch) x N=16pos x K=576 -> omr[27][17] f32
//  3. coeffs -> metaC/metaR [9][16] (overlay dead Xs)
//  4. 18 half-taps: issueG(h+1) | SB | blend(h) | (odd h: mfma(tap), loadA)
//
// LDS per wave (9728 B): Xs @0 (7776) | omr @7776 (1836)
//   phase 3-4 overlay of Xs: metaR @0 (1152) | metaC @1152 (1152) | S @2304
//   (2048; single-buffered — wave-private, DS pipe is in-order).
// ---------------------------------------------------------------------------
__global__ __launch_bounds__(256) void fused(
    const unsigned int* __restrict__ xP,
    const unsigned short* __restrict__ Wom, const unsigned short* __restrict__ W2,
    const float* __restrict__ b_off, const float* __restrict__ b_msk,
    float* __restrict__ out)
{
    __shared__ __align__(16) char lds[38912];    // 4 x 9728
    int tid = threadIdx.x;
    int lane = tid & 63;
    int wv = __builtin_amdgcn_readfirstlane(tid >> 6);
    char* wb = lds + wv * 9728;
    _Float16* XsH = (_Float16*)wb;               // [3][18][72] halves
    float* omr = (float*)(wb + 7776);            // [27][17]
    uint2* metaRw = (uint2*)wb;                  // [9][16]
    uint2* metaCw = (uint2*)(wb + 1152);         // [9][16]
    char* Sw = wb + 2304;                        // [16 pos][64 ch] f16, swizzled

    int g = blockIdx.x * 4 + wv;                 // 4096 tiles
    int b = g >> 9;
    int rem = g & 511;
    int h = rem >> 3;
    int w0 = (rem & 7) << 4;
    int h2 = 2 * h - 1;
    int m16 = lane & 15, q = lane >> 4;

    const unsigned int* xPb_u = xP + (size_t)b * HW * 64;

    // ---- phase 1: stage slab (wave-private; 864 = 3*18*16 items) ----
    for (int u = lane; u < 864; u += 64) {
        int ky = u / 288;
        int rm = u - ky * 288;
        int col = rm >> 4, c4 = rm & 15;
        int hy = h2 + ky, wc = w0 - 1 + col;
        unsigned int lo0 = 0u, lo1 = 0u;
        if ((unsigned)hy < (unsigned)HH && (unsigned)wc < (unsigned)WW) {
            const uint4 gg = *(const uint4*)(xPb_u + ((size_t)hy * WW + wc) * 64 + c4 * 4);
            lo0 = (gg.x & 0xffffu) | (gg.y << 16);
            lo1 = (gg.z & 0xffffu) | (gg.w << 16);
        }
        *(uint2*)(XsH + (ky * 18 + col) * 72 + c4 * 4) = make_uint2(lo0, lo1);
    }
    wave_fence();

    // ---- phase 2: om GEMM  M=32(27) x N=16(m16=pos) x K=576 ----
    {
        floatx4 a0 = (floatx4){0.f, 0.f, 0.f, 0.f};
        floatx4 a1 = (floatx4){0.f, 0.f, 0.f, 0.f};
        const _Float16* wa0 = (const _Float16*)Wom + m16 * 576 + q * 8;
        const _Float16* wa1 = wa0 + 16 * 576;
#pragma unroll
        for (int t = 0; t < 18; ++t) {
            int xs = t >> 1, ky = xs / 3, kx = xs % 3;
            half8 bf = *(const half8*)(XsH + (ky * 18 + m16 + kx) * 72
                                       + (t & 1) * 32 + q * 8);
            half8 af0 = *(const half8*)(wa0 + t * 32);
            half8 af1 = *(const half8*)(wa1 + t * 32);
            a0 = __builtin_amdgcn_mfma_f32_16x16x32_f16(af0, bf, a0, 0, 0, 0);
            a1 = __builtin_amdgcn_mfma_f32_16x16x32_f16(af1, bf, a1, 0, 0, 0);
        }
#pragma unroll
        for (int r = 0; r < 4; ++r) {
            int c0 = q * 4 + r;                  // C/D: col=pos=m16, row=ch
            omr[c0 * 17 + m16] = a0[r];
            if (c0 + 16 < 27) omr[(c0 + 16) * 17 + m16] = a1[r];
        }
    }
    wave_fence();   // omr ready; Xs dead (meta/S overlay from here)

    // ---- phase 3: coeffs + row byte-offsets per (tap, pos 0..15) ----
    for (int u = lane; u < 144; u += 64) {
        int kk = u >> 4, pos = u & 15;
        float offy = omr[(2 * kk) * 17 + pos] + b_off[2 * kk];
        float offx = omr[(2 * kk + 1) * 17 + pos] + b_off[2 * kk + 1];
        float mk = 1.0f / (1.0f + __expf(-(omr[(18 + kk) * 17 + pos] + b_msk[kk])));
        float py = offy + (float)(kk / 3) + (float)h2;
        float px = offx + (float)(kk % 3) + (float)(w0 + pos - 1);

        float y0f = floorf(py), x0f = floorf(px);
        float dy = py - y0f, dx = px - x0f;
        int y0 = (int)y0f, x0 = (int)x0f;
        int y1 = y0 + 1, x1 = x0 + 1;
        bool vy0 = (unsigned)y0 < (unsigned)HH;
        bool vy1 = (unsigned)y1 < (unsigned)HH;
        bool vx0 = (unsigned)x0 < (unsigned)WW;
        bool vx1 = (unsigned)x1 < (unsigned)WW;
        float w00 = (1.0f - dy) * (1.0f - dx) * ((vy0 && vx0) ? mk : 0.0f);
        float w01 = (1.0f - dy) * dx          * ((vy0 && vx1) ? mk : 0.0f);
        float w10 = dy * (1.0f - dx)          * ((vy1 && vx0) ? mk : 0.0f);
        float w11 = dy * dx                   * ((vy1 && vx1) ? mk : 0.0f);
        int xbase = min(max(x0, 0), WW - 2);
        bool s0 = x0 > xbase;
        bool s1 = x1 > xbase;
        float cxA = (s0 ? 0.f : w00) + (s1 ? 0.f : w01);
        float cyA = (s0 ? w00 : 0.f) + (s1 ? w01 : 0.f);
        float cxB = (s0 ? 0.f : w10) + (s1 ? 0.f : w11);
        float cyB = (s0 ? w10 : 0.f) + (s1 ? w11 : 0.f);
        int yc0 = min(max(y0, 0), HH - 1);
        int yc1 = min(max(y1, 0), HH - 1);

        __half2 hA = __floats2half2_rn(cxA, cyA);
        __half2 hB = __floats2half2_rn(cxB, cyB);
        metaCw[u] = make_uint2(__builtin_bit_cast(unsigned int, hA),
                               __builtin_bit_cast(unsigned int, hB));
        metaRw[u] = make_uint2((unsigned)(yc0 * WW + xbase) * 256u,
                               (unsigned)(yc1 * WW + xbase) * 256u);
    }
    wave_fence();

    // ---- phase 4: barrier-free 18 half-tap pipeline ----
    int p = lane & 31;                 // channel-pair (2p, 2p+1)
    int ph4 = (lane >> 5) << 2;        // position sub-block within half-tap
    unsigned int voffC = 8u * (unsigned)p;
    const char* xPb = (const char*)xPb_u;

    floatx4 acc[4];
#pragma unroll
    for (int m = 0; m < 4; ++m) acc[m] = (floatx4){0.f, 0.f, 0.f, 0.f};

    half8 A[8];                        // W2 frags for current tap [m][ks]
    uint2 Ga0[4], Ga1[4], Gb0[4], Gb1[4];   // half-tap gathers, double set

    auto loadA = [&](int k) {
#pragma unroll
        for (int m = 0; m < 4; ++m)
#pragma unroll
            for (int ks = 0; ks < 2; ++ks)
                A[m * 2 + ks] = *(const half8*)((const _Float16*)W2
                    + ((size_t)(k * OC + m * 16 + m16)) * CC + ks * 32 + q * 8);
    };
    auto issueG = [&](int hhk, uint2 (&G0)[4], uint2 (&G1)[4]) {
        int k = hhk >> 1;
#pragma unroll
        for (int i = 0; i < 4; ++i) {
            int rw = ((hhk & 1) << 3) + ph4 + i;          // S row 0..15
            uint2 zw = metaRw[k * 16 + rw];               // bcast per half-wave
            G0[i] = *(const uint2*)(xPb + (zw.x + voffC));
            G1[i] = *(const uint2*)(xPb + (zw.y + voffC));
        }
    };
    auto blend = [&](int hhk, uint2 (&G0)[4], uint2 (&G1)[4]) {
        int k = hhk >> 1;
#pragma unroll
        for (int i = 0; i < 4; ++i) {
            int rw = ((hhk & 1) << 3) + ph4 + i;
            uint2 cf = metaCw[k * 16 + rw];
            __half2 hA = __builtin_bit_cast(__half2, cf.x);
            __half2 hB = __builtin_bit_cast(__half2, cf.y);
            __half2 t0 = __hfma2(hA, __builtin_bit_cast(__half2, G0[i].x),
                                 __hmul2(hB, __builtin_bit_cast(__half2, G1[i].x)));
            __half2 t1 = __hfma2(hA, __builtin_bit_cast(__half2, G0[i].y),
                                 __hmul2(hB, __builtin_bit_cast(__half2, G1[i].y)));
            __half v0 = __hadd(__low2half(t0), __high2half(t0));
            __half v1 = __hadd(__low2half(t1), __high2half(t1));
            unsigned int d = (unsigned int)__builtin_bit_cast(unsigned short, v0)
                           | ((unsigned int)__builtin_bit_cast(unsigned short, v1) << 16);
            *(unsigned int*)(Sw + rw * 128
                + (((p >> 2) ^ (rw & 7)) * 16 + (p & 3) * 4)) = d;
        }
    };
    auto mfma_tap = [&]() {
        half8 Bf0 = *(const half8*)(Sw + m16 * 128 + ((q ^ (m16 & 7)) * 16));
        half8 Bf1 = *(const half8*)(Sw + m16 * 128 + (((4 + q) ^ (m16 & 7)) * 16));
#pragma unroll
        for (int m = 0; m < 4; ++m) {
            acc[m] = __builtin_amdgcn_mfma_f32_16x16x32_f16(A[m * 2 + 0], Bf0, acc[m], 0, 0, 0);
            acc[m] = __builtin_amdgcn_mfma_f32_16x16x32_f16(A[m * 2 + 1], Bf1, acc[m], 0, 0, 0);
        }
    };

    // prologue FIFO: A(0), G(h0). blend(0)'s wait on G(h0) retires A(0) too.
    loadA(0);
    issueG(0, Ga0, Ga1);
#pragma unroll 1
    for (int hh = 0; hh < 18; ++hh) {
        if (hh < 17) {                 // issue next half-tap's gathers FIRST
            if ((hh & 1) == 0) issueG(hh + 1, Gb0, Gb1);
            else               issueG(hh + 1, Ga0, Ga1);
        }
        __builtin_amdgcn_sched_barrier(0);   // pin: issue stays above blend
        if ((hh & 1) == 0) blend(hh, Ga0, Ga1);
        else               blend(hh, Gb0, Gb1);
        if (hh & 1) {
            wave_fence();              // S rows 0..15 written (own DS pipe)
            mfma_tap();                // A(k) already retired by older waits
            if (hh < 17) loadA((hh >> 1) + 1);   // younger than G(hh+1): safe
            __builtin_amdgcn_sched_barrier(0);
        }
    }

    // epilogue: C/D col=m16 (pos), row=q*4+r (o within M-tile)
#pragma unroll
    for (int m = 0; m < 4; ++m)
#pragma unroll
        for (int r = 0; r < 4; ++r) {
            int o = m * 16 + q * 4 + r;
            out[(((size_t)b * OC + o) * HO + h) * WO + w0 + m16] = acc[m][r];
        }
}

// ---------------------------------------------------------------------------
extern "C" void kernel_launch(void* const* d_in, const int* in_sizes, int n_in,
                              void* d_out, int out_size, void* d_ws, size_t ws_size,
                              hipStream_t stream)
{
    const float* x      = (const float*)d_in[0];
    const float* w_off  = (const float*)d_in[1];
    const float* b_off  = (const float*)d_in[2];
    const float* w_msk  = (const float*)d_in[3];
    const float* b_msk  = (const float*)d_in[4];
    const float* w_conv = (const float*)d_in[5];
    float* out = (float*)d_out;

    // workspace (~33.7 MB): xP f16-pair uints, Wom, W2
    unsigned int* xP = (unsigned int*)d_ws;                       // 8*HW*64 * 4B
    unsigned short* Wom = (unsigned short*)(xP + (size_t)BB * HW * 64); // 32*576
    unsigned short* W2 = Wom + 32 * 576;                          // 36864

    prep<<<dim3(2264), dim3(256), 0, stream>>>(x, w_off, w_msk, w_conv,
                                               xP, Wom, W2);
    // 4096 tiles / 4 waves per block = 1024 blocks (round-6 bug: was 2048)
    fused<<<dim3(1024), dim3(256), 0, stream>>>(xP, Wom, W2,
                                                b_off, b_msk, out);
}

// Round 8
// 164.547 us; speedup vs baseline: 1.0218x; 1.0218x over previous
//
#include <hip/hip_runtime.h>
#include <hip/hip_fp16.h>
#include <math.h>

#define BB 8
#define CC 64
#define HH 128
#define WW 128
#define HO 64
#define WO 128
#define OC 64
#define HW (HH * WW)
#define PR 130                 // padded rows  (y: -1..128)
#define PC 130                 // padded cols  (w: -1..128)
#define PLH (PR * PC * 64)     // halves per padded plane

typedef __attribute__((ext_vector_type(4))) float floatx4;
typedef __attribute__((ext_vector_type(8))) _Float16 half8;

__device__ __forceinline__ unsigned short f2h(float f) {
    __half h = __float2half(f);
    return __builtin_bit_cast(unsigned short, h);
}
__device__ __forceinline__ unsigned int pack2(float a, float b) {
    __half2 h = __floats2half2_rn(a, b);
    return __builtin_bit_cast(unsigned int, h);
}
__device__ __forceinline__ unsigned int dup2(float a) {
    __half2 h = __floats2half2_rn(a, a);
    return __builtin_bit_cast(unsigned int, h);
}
// Per-wave fence: drain own LDS ops (in-order DS pipe). No s_barrier in the
// fused main loop — waves are fully independent.
__device__ __forceinline__ void wave_fence() {
    asm volatile("s_waitcnt lgkmcnt(0)" ::: "memory");
}

// ---------------------------------------------------------------------------
// Kernel A (prep):
//  blocks 0..2047   : transpose x -> xH[b][y+1][w+1][c] f16 (padded layout),
//                     b in LOW bits of bx -> XCD i sees mostly plane b=i.
//                     Also zeroes the w=-1 / w=128 border cols of its row.
//  blocks 2048..2119: Wom[32][576] f16
//  blocks 2120..2263: W2[k][o][c] f16
//  blocks 2264..2328: zero the y=-1 and y=128 border rows of all planes
// ---------------------------------------------------------------------------
__global__ __launch_bounds__(256) void prep(
    const float* __restrict__ x,
    const float* __restrict__ w_off, const float* __restrict__ w_msk,
    const float* __restrict__ w_conv,
    unsigned short* __restrict__ xH,
    unsigned short* __restrict__ Wom, unsigned short* __restrict__ W2)
{
    __shared__ float T[66][65];        // [w][c], stride 65: conflict-free
    int tid = threadIdx.x, bx = blockIdx.x;
    if (bx < 2048) {
        int b = bx & 7, y = (bx >> 3) & 127, wh = bx >> 10;
        int w0 = wh << 6;
        const float* xb = x + (((size_t)b * CC) * HH + y) * WW + w0;
        unsigned short* xhb = xH + (size_t)b * PLH;
#pragma unroll
        for (int i = 0; i < 4; ++i) {
            int idx = i * 256 + tid;             // 0..1023
            int cch = idx >> 4, f4 = (idx & 15) << 2;
            floatx4 v = *(const floatx4*)(xb + (size_t)cch * HW + f4);
            T[f4 + 0][cch] = v.x;
            T[f4 + 1][cch] = v.y;
            T[f4 + 2][cch] = v.z;
            T[f4 + 3][cch] = v.w;
        }
        __syncthreads();
        // phase B: thread = (w, 8-ch block); 2x b128 LDS read -> uint4 store
        int c8 = tid & 7, wr = tid >> 3;         // wr 0..31
#pragma unroll
        for (int j = 0; j < 2; ++j) {
            int w = j * 32 + wr;
            floatx4 a = *(const floatx4*)&T[w][8 * c8];
            floatx4 c = *(const floatx4*)&T[w][8 * c8 + 4];
            uint4 d;
            d.x = pack2(a.x, a.y);
            d.y = pack2(a.z, a.w);
            d.z = pack2(c.x, c.y);
            d.w = pack2(c.z, c.w);
            *(uint4*)(xhb + ((size_t)(y + 1) * PC + (w0 + w + 1)) * 64 + 8 * c8) = d;
        }
        // border cols of this row: wh0 -> padded col 0 ; wh1 -> padded col 129
        if (tid < 8) {
            uint4 z = make_uint4(0u, 0u, 0u, 0u);
            int pcol = (wh == 0) ? 0 : 129;
            *(uint4*)(xhb + ((size_t)(y + 1) * PC + pcol) * 64 + 8 * tid) = z;
        }
    } else if (bx < 2120) {
        int i = (bx - 2048) * 256 + tid;     // < 18432 = 32*576
        int chn = i / 576, kk = i % 576;
        int xs = kk >> 6, cc = kk & 63;
        float v = 0.0f;
        if (chn < 18)      v = w_off[(chn * CC + cc) * 9 + xs];
        else if (chn < 27) v = w_msk[((chn - 18) * CC + cc) * 9 + xs];
        Wom[i] = f2h(v);
    } else if (bx < 2264) {
        int i = (bx - 2120) * 256 + tid;     // < 36864
        int k = i % 9, cc = (i / 9) % CC, o = i / (CC * 9);
        W2[((size_t)k * OC + o) * CC + cc] = f2h(w_conv[i]);
    } else {
        // zero border rows y=-1 (prow 0) and y=128 (prow 129), all planes.
        // 8 planes * 2 rows * 130 cols * 64 ch = 133120 halves = 65*2048.
        int i = (bx - 2264) * 2048 + tid * 8;
        int b = i / 16640;
        int r = i - b * 16640;
        int prow = (r < 8320) ? 0 : 129;
        int rr = (r < 8320) ? r : r - 8320;
        uint4 z = make_uint4(0u, 0u, 0u, 0u);
        *(uint4*)(xH + (size_t)b * PLH + (size_t)prow * PC * 64 + rr) = z;
    }
}

// ---------------------------------------------------------------------------
// Kernel B (fused), round-8: independent waves (round-7 structure) with
//  * XCD affinity: b = bx&7 (round-3's accidental win, now deliberate).
//    Each XCD's working plane = 2.16 MB < its 4 MB L2 -> gathers are L2 hits.
//  * NO slab staging: om-GEMM B-frags read directly from padded xH (global,
//    L2-hot; zero border makes edge taps safe). LDS 38.9 -> 22.5 KB/block.
//  * gathers: 4 x 8B per (pos, 4ch) via offset:0/128 immediates; blend is
//    pure pk_fma (coeffs pre-duplicated), no horizontal add.
//
// Per-wave LDS region (5632 B): metaR uint2[144] @0 | metaC uint4[144] @1152
//   | omr[27][17] f32 @3456 (phases 2-3) / S[16][64] f16 @3456 (phase 4).
// Block: 4 waves x 5632 = 22528 B.
// ---------------------------------------------------------------------------
__global__ __launch_bounds__(256) void fused(
    const unsigned short* __restrict__ xH,
    const unsigned short* __restrict__ Wom, const unsigned short* __restrict__ W2,
    const float* __restrict__ b_off, const float* __restrict__ b_msk,
    float* __restrict__ out)
{
    __shared__ __align__(16) char lds[22528];    // 4 x 5632
    int tid = threadIdx.x;
    int lane = tid & 63;
    int wv = __builtin_amdgcn_readfirstlane(tid >> 6);
    char* wb = lds + wv * 5632;
    uint2* metaRw = (uint2*)wb;                  // [9][16]
    uint4* metaCw = (uint4*)(wb + 1152);         // [9][16]
    float* omr = (float*)(wb + 3456);            // [27][17]
    char* Sw = wb + 3456;                        // [16 pos][64 ch] f16 (ph 4)

    int bx = blockIdx.x;               // 1024 = 2wh * 64h * 8b  (b LOW bits)
    int b = bx & 7;
    int r2 = bx >> 3;                  // 0..127
    int h = r2 >> 1;
    int w0 = ((r2 & 1) << 6) + wv * 16;
    int h2 = 2 * h - 1;
    int m16 = lane & 15, q = lane >> 4;

    const unsigned short* xHb = xH + (size_t)b * PLH;

    // ---- phase 1 (om GEMM): M=32(27) x N=16(m16=pos) x K=576, B from global
    {
        floatx4 a0 = (floatx4){0.f, 0.f, 0.f, 0.f};
        floatx4 a1 = (floatx4){0.f, 0.f, 0.f, 0.f};
        const _Float16* wa0 = (const _Float16*)Wom + m16 * 576 + q * 8;
        const _Float16* wa1 = wa0 + 16 * 576;
        // per-lane col base: padded col = (w0-1+m16)+1 = w0+m16
        const _Float16* xcol = (const _Float16*)xHb + ((size_t)w0 + m16) * 64 + q * 8;
#pragma unroll
        for (int t = 0; t < 18; ++t) {
            int xs = t >> 1, ky = xs / 3, kx = xs % 3;
            // padded row = h2+ky+1 ; chunk = (t&1)*32
            half8 bf = *(const half8*)(xcol + ((size_t)(h2 + ky + 1) * PC + kx) * 64
                                       + (t & 1) * 32);
            half8 af0 = *(const half8*)(wa0 + t * 32);
            half8 af1 = *(const half8*)(wa1 + t * 32);
            a0 = __builtin_amdgcn_mfma_f32_16x16x32_f16(af0, bf, a0, 0, 0, 0);
            a1 = __builtin_amdgcn_mfma_f32_16x16x32_f16(af1, bf, a1, 0, 0, 0);
        }
#pragma unroll
        for (int r = 0; r < 4; ++r) {
            int c0 = q * 4 + r;                  // C/D: col=pos=m16, row=ch
            omr[c0 * 17 + m16] = a0[r];
            if (c0 + 16 < 27) omr[(c0 + 16) * 17 + m16] = a1[r];
        }
    }
    wave_fence();

    // ---- phase 2: coeffs (duplicated half2) + row byte-offsets ----
    for (int u = lane; u < 144; u += 64) {
        int kk = u >> 4, pos = u & 15;
        float offy = omr[(2 * kk) * 17 + pos] + b_off[2 * kk];
        float offx = omr[(2 * kk + 1) * 17 + pos] + b_off[2 * kk + 1];
        float mk = 1.0f / (1.0f + __expf(-(omr[(18 + kk) * 17 + pos] + b_msk[kk])));
        float py = offy + (float)(kk / 3) + (float)h2;
        float px = offx + (float)(kk % 3) + (float)(w0 + pos - 1);

        float y0f = floorf(py), x0f = floorf(px);
        float dy = py - y0f, dx = px - x0f;
        int y0 = (int)y0f, x0 = (int)x0f;
        int y1 = y0 + 1, x1 = x0 + 1;
        bool vy0 = (unsigned)y0 < (unsigned)HH;
        bool vy1 = (unsigned)y1 < (unsigned)HH;
        bool vx0 = (unsigned)x0 < (unsigned)WW;
        bool vx1 = (unsigned)x1 < (unsigned)WW;
        float w00 = (1.0f - dy) * (1.0f - dx) * ((vy0 && vx0) ? mk : 0.0f);
        float w01 = (1.0f - dy) * dx          * ((vy0 && vx1) ? mk : 0.0f);
        float w10 = dy * (1.0f - dx)          * ((vy1 && vx0) ? mk : 0.0f);
        float w11 = dy * dx                   * ((vy1 && vx1) ? mk : 0.0f);
        int xbase = min(max(x0, 0), WW - 2);
        bool s0 = x0 > xbase;
        bool s1 = x1 > xbase;
        float cxA = (s0 ? 0.f : w00) + (s1 ? 0.f : w01);
        float cyA = (s0 ? w00 : 0.f) + (s1 ? w01 : 0.f);
        float cxB = (s0 ? 0.f : w10) + (s1 ? 0.f : w11);
        float cyB = (s0 ? w10 : 0.f) + (s1 ? w11 : 0.f);
        int yc0 = min(max(y0, 0), HH - 1);
        int yc1 = min(max(y1, 0), HH - 1);

        metaCw[u] = make_uint4(dup2(cxA), dup2(cyA), dup2(cxB), dup2(cyB));
        // byte offsets into padded plane: ((y+1)*130 + (x+1)) * 128
        metaRw[u] = make_uint2((unsigned)((yc0 + 1) * PC + xbase + 1) * 128u,
                               (unsigned)((yc1 + 1) * PC + xbase + 1) * 128u);
    }
    wave_fence();

    // ---- phase 3: barrier-free 18 half-tap pipeline ----
    int p16 = m16;                     // 4-ch block: ch 4*p16..+3
    int pg = q;                        // position-in-group (4 pos / group)
    unsigned int voffC = 8u * (unsigned)p16;
    const char* xPb = (const char*)xHb;

    floatx4 acc[4];
#pragma unroll
    for (int m = 0; m < 4; ++m) acc[m] = (floatx4){0.f, 0.f, 0.f, 0.f};

    half8 A[8];                        // W2 frags current tap [m][ks]
    uint2 Ga[2][4], Gb[2][4];          // half-tap gathers: [grp][corner]

    auto loadA = [&](int k) {
#pragma unroll
        for (int m = 0; m < 4; ++m)
#pragma unroll
            for (int ks = 0; ks < 2; ++ks)
                A[m * 2 + ks] = *(const half8*)((const _Float16*)W2
                    + ((size_t)(k * OC + m * 16 + m16)) * CC + ks * 32 + q * 8);
    };
    auto issueG = [&](int hhk, uint2 (&G)[2][4]) {
        int k = hhk >> 1;
#pragma unroll
        for (int grp = 0; grp < 2; ++grp) {
            int rw = ((hhk & 1) << 3) + grp * 4 + pg;     // pos row 0..15
            uint2 zw = metaRw[k * 16 + rw];               // bcast per quarter
            const char* r0 = xPb + (zw.x + voffC);
            const char* r1 = xPb + (zw.y + voffC);
            G[grp][0] = *(const uint2*)(r0);              // y0, x
            G[grp][1] = *(const uint2*)(r0 + 128);        // y0, x+1
            G[grp][2] = *(const uint2*)(r1);              // y1, x
            G[grp][3] = *(const uint2*)(r1 + 128);        // y1, x+1
        }
    };
    auto blend = [&](int hhk, uint2 (&G)[2][4]) {
        int k = hhk >> 1;
#pragma unroll
        for (int grp = 0; grp < 2; ++grp) {
            int rw = ((hhk & 1) << 3) + grp * 4 + pg;
            uint4 cf = metaCw[k * 16 + rw];               // bcast b128
            __half2 cA = __builtin_bit_cast(__half2, cf.x);
            __half2 cB = __builtin_bit_cast(__half2, cf.y);
            __half2 cC = __builtin_bit_cast(__half2, cf.z);
            __half2 cD = __builtin_bit_cast(__half2, cf.w);
            __half2 lo = __hmul2(cA, __builtin_bit_cast(__half2, G[grp][0].x));
            lo = __hfma2(cB, __builtin_bit_cast(__half2, G[grp][1].x), lo);
            lo = __hfma2(cC, __builtin_bit_cast(__half2, G[grp][2].x), lo);
            lo = __hfma2(cD, __builtin_bit_cast(__half2, G[grp][3].x), lo);
            __half2 hi = __hmul2(cA, __builtin_bit_cast(__half2, G[grp][0].y));
            hi = __hfma2(cB, __builtin_bit_cast(__half2, G[grp][1].y), hi);
            hi = __hfma2(cC, __builtin_bit_cast(__half2, G[grp][2].y), hi);
            hi = __hfma2(cD, __builtin_bit_cast(__half2, G[grp][3].y), hi);
            // S write: 4 ch = 8 B = half of a 16-B block; block-XOR swizzle
            unsigned int soff = (unsigned)(rw * 128
                + (((p16 >> 1) ^ (rw & 7)) * 16 + (p16 & 1) * 8));
            *(uint2*)(Sw + soff) = make_uint2(__builtin_bit_cast(unsigned int, lo),
                                              __builtin_bit_cast(unsigned int, hi));
        }
    };
    auto mfma_tap = [&]() {
        half8 Bf0 = *(const half8*)(Sw + m16 * 128 + ((q ^ (m16 & 7)) * 16));
        half8 Bf1 = *(const half8*)(Sw + m16 * 128 + (((4 + q) ^ (m16 & 7)) * 16));
#pragma unroll
        for (int m = 0; m < 4; ++m) {
            acc[m] = __builtin_amdgcn_mfma_f32_16x16x32_f16(A[m * 2 + 0], Bf0, acc[m], 0, 0, 0);
            acc[m] = __builtin_amdgcn_mfma_f32_16x16x32_f16(A[m * 2 + 1], Bf1, acc[m], 0, 0, 0);
        }
    };

    // prologue FIFO: A(0), G(h0). blend(0)'s wait on G(h0) retires A(0) too.
    loadA(0);
    issueG(0, Ga);
#pragma unroll 1
    for (int hh = 0; hh < 18; ++hh) {
        if (hh < 17) {                 // issue next half-tap's gathers FIRST
            if ((hh & 1) == 0) issueG(hh + 1, Gb);
            else               issueG(hh + 1, Ga);
        }
        __builtin_amdgcn_sched_barrier(0);   // pin: issue stays above blend
        if ((hh & 1) == 0) blend(hh, Ga);
        else               blend(hh, Gb);
        if (hh & 1) {
            wave_fence();              // S rows written (own DS pipe)
            mfma_tap();                // A(k) already retired by older waits
            if (hh < 17) loadA((hh >> 1) + 1);   // younger than G(hh+1): safe
            __builtin_amdgcn_sched_barrier(0);
        }
    }

    // epilogue: C/D col=m16 (pos), row=q*4+r (o within M-tile)
#pragma unroll
    for (int m = 0; m < 4; ++m)
#pragma unroll
        for (int r = 0; r < 4; ++r) {
            int o = m * 16 + q * 4 + r;
            out[(((size_t)b * OC + o) * HO + h) * WO + w0 + m16] = acc[m][r];
        }
}

// ---------------------------------------------------------------------------
extern "C" void kernel_launch(void* const* d_in, const int* in_sizes, int n_in,
                              void* d_out, int out_size, void* d_ws, size_t ws_size,
                              hipStream_t stream)
{
    const float* x      = (const float*)d_in[0];
    const float* w_off  = (const float*)d_in[1];
    const float* b_off  = (const float*)d_in[2];
    const float* w_msk  = (const float*)d_in[3];
    const float* b_msk  = (const float*)d_in[4];
    const float* w_conv = (const float*)d_in[5];
    float* out = (float*)d_out;

    // workspace (~17.4 MB): padded xH f16, Wom, W2
    unsigned short* xH = (unsigned short*)d_ws;                  // 8*PLH halves
    unsigned short* Wom = xH + (size_t)BB * PLH;                 // 32*576
    unsigned short* W2 = Wom + 32 * 576;                         // 36864

    prep<<<dim3(2329), dim3(256), 0, stream>>>(x, w_off, w_msk, w_conv,
                                               xH, Wom, W2);
    // 4096 tiles / 4 waves per block = 1024 blocks; b in LOW 3 bits
    fused<<<dim3(1024), dim3(256), 0, stream>>>(xH, Wom, W2,
                                                b_off, b_msk, out);
}

// Round 9
// 141.965 us; speedup vs baseline: 1.1843x; 1.1591x over previous
//
#include <hip/hip_runtime.h>
#include <hip/hip_fp16.h>
#include <math.h>

#define BB 8
#define CC 64
#define HH 128
#define WW 128
#define HO 64
#define WO 128
#define OC 64
#define HW (HH * WW)

typedef __attribute__((ext_vector_type(4))) float floatx4;
typedef __attribute__((ext_vector_type(8))) _Float16 half8;

__device__ __forceinline__ unsigned short f2h(float f) {
    __half h = __float2half(f);
    return __builtin_bit_cast(unsigned short, h);
}
__device__ __forceinline__ unsigned int packpair(float a, float b) {
    __half2 h = __floats2half2_rn(a, b);   // lo=a hi=b
    return __builtin_bit_cast(unsigned int, h);
}
// Barrier that drains ONLY LDS ops: global loads stay in flight across it.
__device__ __forceinline__ void lgkm_barrier() {
    asm volatile("s_waitcnt lgkmcnt(0)" ::: "memory");
    __builtin_amdgcn_s_barrier();
}

// ---------------------------------------------------------------------------
// Kernel A (prep) — the validated R5 version (xP pair-packed fp16, uint4
// stores, conflict-free T[w][c] stride-65 transpose).
// ---------------------------------------------------------------------------
__global__ __launch_bounds__(256) void prep(
    const float* __restrict__ x,
    const float* __restrict__ w_off, const float* __restrict__ w_msk,
    const float* __restrict__ w_conv,
    unsigned int* __restrict__ xP,
    unsigned short* __restrict__ Wom, unsigned short* __restrict__ W2)
{
    __shared__ float T[66][65];        // [w 0..64][c 0..63], stride 65
    int tid = threadIdx.x, bx = blockIdx.x;
    if (bx < 2048) {
        int wh = bx & 1, b = (bx >> 1) & 7, y = bx >> 4;
        int w0 = wh << 6;
        const float* xb = x + (((size_t)b * CC) * HH + y) * WW + w0;
#pragma unroll
        for (int i = 0; i < 4; ++i) {
            int idx = i * 256 + tid;             // 0..1023
            int cch = idx >> 4, f4 = (idx & 15) << 2;
            floatx4 v = *(const floatx4*)(xb + (size_t)cch * HW + f4);
            T[f4 + 0][cch] = v.x;
            T[f4 + 1][cch] = v.y;
            T[f4 + 2][cch] = v.z;
            T[f4 + 3][cch] = v.w;
        }
        if (tid < 64) {
            float e = 0.0f;
            if (w0 + 64 < WW) e = xb[(size_t)tid * HW + 64];
            T[64][tid] = e;
        }
        __syncthreads();
        int c4 = tid & 15;             // channel block (4c4..4c4+3)
        int wr = tid >> 4;             // 0..15
        size_t rowbase = (((size_t)b * HH + y) * WW) + w0;
#pragma unroll
        for (int j = 0; j < 4; ++j) {
            int w = 16 * j + wr;
            floatx4 a  = *(const floatx4*)&T[w][4 * c4];
            floatx4 bb = *(const floatx4*)&T[w + 1][4 * c4];
            uint4 d;
            d.x = packpair(a.x, bb.x);
            d.y = packpair(a.y, bb.y);
            d.z = packpair(a.z, bb.z);
            d.w = packpair(a.w, bb.w);
            *(uint4*)(xP + (rowbase + w) * 64 + 4 * c4) = d;
        }
    } else if (bx < 2120) {
        int i = (bx - 2048) * 256 + tid;     // < 18432 = 32*576
        int chn = i / 576, kk = i % 576;
        int xs = kk >> 6, cc = kk & 63;
        float v = 0.0f;
        if (chn < 18)      v = w_off[(chn * CC + cc) * 9 + xs];
        else if (chn < 27) v = w_msk[((chn - 18) * CC + cc) * 9 + xs];
        Wom[i] = f2h(v);
    } else {
        int i = (bx - 2120) * 256 + tid;     // < 36864
        int k = i % 9, cc = (i / 9) % CC, o = i / (CC * 9);
        W2[((size_t)k * OC + o) * CC + cc] = f2h(w_conv[i]);
    }
}

// ---------------------------------------------------------------------------
// Kernel B (fused) — the proven round-3 schedule (53 µs: full-unroll 9 taps,
// depth-2 gather pipeline, af rotation 2 taps ahead, lgkm-only barriers)
// plus ONE change: metaR row-offsets prefetched into SGPRs two taps ahead
// (rolling 2x16 uniform words). The per-tap "ds_read meta -> readfirstlane
// -> address -> gather" dependency chain is off the critical path; gathers
// issue from scalar base + shared voffset with zero LDS wait.
// ---------------------------------------------------------------------------
__global__ __launch_bounds__(256, 4) void fused(
    const unsigned int* __restrict__ xP,
    const unsigned short* __restrict__ Wom, const unsigned short* __restrict__ W2,
    const float* __restrict__ b_off, const float* __restrict__ b_msk,
    float* __restrict__ out)
{
    __shared__ __align__(16) char lds[18304];
    typedef _Float16 XsRow[34][72];
    XsRow* Xs = (XsRow*)lds;                                        // [3][34][72]
    unsigned short (*S)[32][64] = (unsigned short(*)[32][64])lds;   // [2][32][64]
    uint2* metaC = (uint2*)(lds + 8192);                            // 288*8
    uint2* metaR = (uint2*)(lds + 10496);                           // 288*8
    float (*omr)[33] = (float(*)[33])(lds + 14720);                 // [27][33]

    int tid = threadIdx.x;
    int lane = tid & 63;
    int wv = __builtin_amdgcn_readfirstlane(tid >> 6);
    int bx = blockIdx.x;               // 2048 = 8b * 64h * 4wt (b LOW bits:
    int b = bx & 7;                    // XCD i works plane i -> L2-local)
    int rest = bx >> 3;
    int h = rest >> 2;
    int w0 = (rest & 3) * 32;
    int h2 = 2 * h - 1;
    int m16 = lane & 15, q = lane >> 4;

    const unsigned int* xPb_u = xP + (size_t)b * HW * 64;

    // ---- phase 1: stage slab from xP pair-lows (uint4 coalesced) ----
    for (int u = tid; u < 1632; u += 256) {      // 1632 = 3*34*16
        int ky = u / 544;
        int rem = u - ky * 544;
        int col = rem >> 4, c4 = rem & 15;
        int hy = h2 + ky, wc = w0 - 1 + col;
        unsigned int lo0 = 0u, lo1 = 0u;
        if ((unsigned)hy < (unsigned)HH && (unsigned)wc < (unsigned)WW) {
            const uint4 g = *(const uint4*)(xPb_u + ((size_t)hy * WW + wc) * 64 + c4 * 4);
            lo0 = (g.x & 0xffffu) | (g.y << 16);
            lo1 = (g.z & 0xffffu) | (g.w << 16);
        }
        uint2* dst = (uint2*)((unsigned short*)lds + ((ky * 34 + col) * 72 + c4 * 4));
        *dst = make_uint2(lo0, lo1);
    }
    lgkm_barrier();

    // ---- phase 2: om GEMM (wave = 2 Mtiles x 2 Ntiles, K=576) ----
    {
        int mt = wv & 1, nt = wv >> 1;
        floatx4 a = (floatx4){0.f, 0.f, 0.f, 0.f};
        const _Float16* wa = (const _Float16*)Wom + (mt * 16 + m16) * 576 + q * 8;
#pragma unroll
        for (int t = 0; t < 18; ++t) {
            int xs = t >> 1, ky = xs / 3, kx = xs % 3;
            half8 af = *(const half8*)(wa + t * 32);
            half8 bf = *(const half8*)&Xs[ky][nt * 16 + m16 + kx][(t & 1) * 32 + q * 8];
            a = __builtin_amdgcn_mfma_f32_16x16x32_f16(af, bf, a, 0, 0, 0);
        }
#pragma unroll
        for (int r = 0; r < 4; ++r) {
            int chn = mt * 16 + q * 4 + r;
            if (chn < 27) omr[chn][nt * 16 + m16] = a[r];
        }
    }
    lgkm_barrier();   // omr ready; Xs reads done (meta/S may overlay)

    // ---- phase 3: coeffs (half2) + packed row byte-offsets per (tap,pos) ----
    for (int u = tid; u < 288; u += 256) {
        int kk = u >> 5, pos = u & 31;
        float offy = omr[2 * kk][pos] + b_off[2 * kk];
        float offx = omr[2 * kk + 1][pos] + b_off[2 * kk + 1];
        float mk = 1.0f / (1.0f + __expf(-(omr[18 + kk][pos] + b_msk[kk])));
        float py = offy + (float)(kk / 3) + (float)h2;
        float px = offx + (float)(kk % 3) + (float)(w0 + pos - 1);

        float y0f = floorf(py), x0f = floorf(px);
        float dy = py - y0f, dx = px - x0f;
        int y0 = (int)y0f, x0 = (int)x0f;
        int y1 = y0 + 1, x1 = x0 + 1;
        bool vy0 = (unsigned)y0 < (unsigned)HH;
        bool vy1 = (unsigned)y1 < (unsigned)HH;
        bool vx0 = (unsigned)x0 < (unsigned)WW;
        bool vx1 = (unsigned)x1 < (unsigned)WW;
        float w00 = (1.0f - dy) * (1.0f - dx) * ((vy0 && vx0) ? mk : 0.0f);
        float w01 = (1.0f - dy) * dx          * ((vy0 && vx1) ? mk : 0.0f);
        float w10 = dy * (1.0f - dx)          * ((vy1 && vx0) ? mk : 0.0f);
        float w11 = dy * dx                   * ((vy1 && vx1) ? mk : 0.0f);
        int xbase = min(max(x0, 0), WW - 2);
        bool s0 = x0 > xbase;
        bool s1 = x1 > xbase;
        float cxA = (s0 ? 0.f : w00) + (s1 ? 0.f : w01);
        float cyA = (s0 ? w00 : 0.f) + (s1 ? w01 : 0.f);
        float cxB = (s0 ? 0.f : w10) + (s1 ? 0.f : w11);
        float cyB = (s0 ? w10 : 0.f) + (s1 ? w11 : 0.f);
        int yc0 = min(max(y0, 0), HH - 1);
        int yc1 = min(max(y1, 0), HH - 1);

        __half2 hA = __floats2half2_rn(cxA, cyA);
        __half2 hB = __floats2half2_rn(cxB, cyB);
        metaC[u] = make_uint2(__builtin_bit_cast(unsigned int, hA),
                              __builtin_bit_cast(unsigned int, hB));
        metaR[u] = make_uint2((unsigned)(yc0 * WW + xbase) * 256u,
                              (unsigned)(yc1 * WW + xbase) * 256u);
    }
    lgkm_barrier();

    // ---- phase 4: depth-2 pipelined sampling + main MFMA ----
    int p0 = wv * 8;                   // my 8 positions
    const char* xPb = (const char*)xPb_u;
    unsigned int voff = 4u * (unsigned)lane;
    floatx4 acc0 = (floatx4){0.f, 0.f, 0.f, 0.f};
    floatx4 acc1 = (floatx4){0.f, 0.f, 0.f, 0.f};

    unsigned int Ga0[8], Ga1[8], Gb0[8], Gb1[8];
    half8 afr[3][2];                   // rotating W2 prefetch, 2 taps ahead
    const _Float16* W2w = (const _Float16*)W2 + ((size_t)wv * 16 + m16) * CC + q * 8;

    // rolling SGPR meta: set s=k&1 holds tap k's 8 row-offset pairs.
    // Fetched >=1 tap before use (ds latency + readfirstlane hidden).
    unsigned sRx[2][8], sRy[2][8];

    auto loadaf = [&](int k, int slot) {
#pragma unroll
        for (int s = 0; s < 2; ++s)
            afr[slot][s] = *(const half8*)(W2w + (size_t)k * (OC * CC) + s * 32);
    };
    auto fetchMeta = [&](int k, int s) {
#pragma unroll
        for (int i = 0; i < 8; ++i) {
            uint2 zw = metaR[k * 32 + p0 + i];           // broadcast ds_read
            sRx[s][i] = (unsigned)__builtin_amdgcn_readfirstlane((int)zw.x);
            sRy[s][i] = (unsigned)__builtin_amdgcn_readfirstlane((int)zw.y);
        }
    };
    auto issue = [&](int k, unsigned int (&A0)[8], unsigned int (&A1)[8]) {
        int s = k & 1;
#pragma unroll
        for (int i = 0; i < 8; ++i) {
            A0[i] = *(const unsigned int*)(xPb + sRx[s][i] + voff);  // saddr+voff
            A1[i] = *(const unsigned int*)(xPb + sRy[s][i] + voff);
        }
    };
    auto dostore = [&](int k, int buf, unsigned int (&A0)[8], unsigned int (&A1)[8]) {
#pragma unroll
        for (int i = 0; i < 8; ++i) {
            uint2 cf = metaC[k * 32 + p0 + i];           // broadcast ds_read
            __half2 hA = __builtin_bit_cast(__half2, cf.x);
            __half2 hB = __builtin_bit_cast(__half2, cf.y);
            __half2 g0 = __builtin_bit_cast(__half2, A0[i]);
            __half2 g1 = __builtin_bit_cast(__half2, A1[i]);
            __half2 p = __hfma2(hA, g0, __hmul2(hB, g1));   // v_pk_fma_f16
            __half sv = __hadd(__low2half(p), __high2half(p));
            int pos = p0 + i;
            S[buf][pos][((lane >> 3) ^ (pos & 7)) * 8 + (lane & 7)] =
                __builtin_bit_cast(unsigned short, sv);
        }
    };
    auto mfma_step = [&](int k, int buf, int slot) {
#pragma unroll
        for (int s = 0; s < 2; ++s) {
            half8 af = afr[slot][s];
            int cb = ((q + 4 * s) ^ (m16 & 7)) * 8;
            half8 bf0 = *(const half8*)&S[buf][m16][cb];
            half8 bf1 = *(const half8*)&S[buf][16 + m16][cb];
            acc0 = __builtin_amdgcn_mfma_f32_16x16x32_f16(af, bf0, acc0, 0, 0, 0);
            acc1 = __builtin_amdgcn_mfma_f32_16x16x32_f16(af, bf1, acc1, 0, 0, 0);
        }
    };

    // prologue. vmem FIFO: af(0) af(1) G(0) [wait G(0) retires af0,af1] G(1)
    loadaf(0, 0);
    loadaf(1, 1);
    fetchMeta(0, 0);
    fetchMeta(1, 1);
    issue(0, Ga0, Ga1);
    dostore(0, 0, Ga0, Ga1);
    fetchMeta(2, 0);                   // meta(0) consumed; set 0 free
    issue(1, Gb0, Gb1);
#pragma unroll
    for (int k = 0; k < 9; ++k) {
        lgkm_barrier();                // S[k&1] visible; gathers keep flying
        if (k < 7) {
            loadaf(k + 2, (k + 2) % 3);              // af ahead of its G
            if ((k & 1) == 0) issue(k + 2, Ga0, Ga1);
            else              issue(k + 2, Gb0, Gb1);
        }
        if (k < 6) fetchMeta(k + 3, (k + 3) & 1);    // for issue at tap k+1
        mfma_step(k, k & 1, k % 3);                  // no vmem wait here
        if (k < 8) {
            if ((k & 1) == 0) dostore(k + 1, 1, Gb0, Gb1);
            else              dostore(k + 1, 0, Ga0, Ga1);
        }
    }

    // epilogue: C/D col=lane&15 (pos), row=(lane>>4)*4+reg (o)
#pragma unroll
    for (int nt = 0; nt < 2; ++nt) {
        floatx4 av = nt ? acc1 : acc0;
#pragma unroll
        for (int r = 0; r < 4; ++r) {
            int o = wv * 16 + q * 4 + r;
            out[(((size_t)b * OC + o) * HO + h) * WO + w0 + nt * 16 + m16] = av[r];
        }
    }
}

// ---------------------------------------------------------------------------
extern "C" void kernel_launch(void* const* d_in, const int* in_sizes, int n_in,
                              void* d_out, int out_size, void* d_ws, size_t ws_size,
                              hipStream_t stream)
{
    const float* x      = (const float*)d_in[0];
    const float* w_off  = (const float*)d_in[1];
    const float* b_off  = (const float*)d_in[2];
    const float* w_msk  = (const float*)d_in[3];
    const float* b_msk  = (const float*)d_in[4];
    const float* w_conv = (const float*)d_in[5];
    float* out = (float*)d_out;

    // workspace (~33.7 MB): xP f16-pair uints, Wom, W2
    unsigned int* xP = (unsigned int*)d_ws;                       // 8*HW*64 * 4B
    unsigned short* Wom = (unsigned short*)(xP + (size_t)BB * HW * 64); // 32*576
    unsigned short* W2 = Wom + 32 * 576;                          // 36864

    prep<<<dim3(2264), dim3(256), 0, stream>>>(x, w_off, w_msk, w_conv,
                                               xP, Wom, W2);
    fused<<<dim3(2048), dim3(256), 0, stream>>>(xP, Wom, W2,
                                                b_off, b_msk, out);
}